// Round 1
// baseline (197.125 us; speedup 1.0000x reference)
//
#include <hip/hip_runtime.h>
#include <float.h>

#define H 64
#define W 512
#define SPLIT 4   // blocks per (tensor,h): 64*4 = 256 blocks per tensor

// ---------------------------------------------------------------------------
// Kernel 1: fused masked-exp-norm row statistics.
// For each row i of the [H,W,W] cost volume computes, WITHOUT materializing att:
//   disp_ini[i] = i - sum_j att[i,j]*j
//   colsum[j]  += sum_i att[i,j]        (-> valid mask, thresholded later)
//   raw[i]      = 3-tap subpixel around argmax (gen_raw_disp fused)
// LOWER=true: tril mask (valid j<=i), pos = max(p_i-p_j,0)   [cost2 -> att_r2l]
// LOWER=false: triu mask (valid j>=i), pos = max(p_j-p_i,0)  [cost1 -> att_l2r]
// ---------------------------------------------------------------------------
template<bool LOWER>
__global__ __launch_bounds__(512) void attn_stats(
    const float* __restrict__ cost,
    float* __restrict__ disp_ini,   // [H*W]
    float* __restrict__ colsum,     // [H*W], pre-zeroed, global-atomic accum
    float* __restrict__ raw)        // [H*W] (points into d_out channel)
{
  __shared__ float scol[W];
  const int tid  = threadIdx.x;
  const int lane = tid & 63;
  const int wid  = tid >> 6;           // 0..7
  const int h    = blockIdx.x / SPLIT;
  const int s    = blockIdx.x % SPLIT;
  scol[tid] = 0.f;
  __syncthreads();

  float cacc[8] = {0,0,0,0,0,0,0,0};
  const float pscale = 2.0f / 511.0f;  // linspace(0,2,512) step
  const float* hb = cost + (size_t)h * W * W;

  int jmap[8];
  #pragma unroll
  for (int k = 0; k < 8; k++)
    jmap[k] = (k < 4) ? (lane * 4 + k) : (256 + lane * 4 + (k - 4));

  for (int t = wid; t < W / SPLIT; t += 8) {
    const int i = s * (W / SPLIT) + t;
    const float* rp = hb + (size_t)i * W;
    const float4 va = ((const float4*)rp)[lane];       // j = lane*4+k
    const float4 vb = ((const float4*)rp)[64 + lane];  // j = 256+lane*4+k
    float c[8] = {va.x, va.y, va.z, va.w, vb.x, vb.y, vb.z, vb.w};

    bool vld[8];
    float mx = -FLT_MAX;
    #pragma unroll
    for (int k = 0; k < 8; k++) {
      vld[k] = LOWER ? (jmap[k] <= i) : (jmap[k] >= i);
      if (vld[k] && c[k] > mx) mx = c[k];
    }
    #pragma unroll
    for (int off = 32; off; off >>= 1) mx = fmaxf(mx, __shfl_xor(mx, off));
    // tril/triu zeros participate in the row max whenever the row has any
    if (LOWER ? (i < W - 1) : (i > 0)) mx = fmaxf(mx, 0.f);

    float e[8];
    float ssum = 0.f, wsum = 0.f, bv = -1.f;
    int bi = 0;
    #pragma unroll
    for (int k = 0; k < 8; k++) {
      e[k] = vld[k] ? __expf(c[k] - mx) : 0.f;
      ssum += e[k];
      wsum += e[k] * (float)jmap[k];
      if (e[k] > bv) { bv = e[k]; bi = jmap[k]; }  // strict > = first occurrence
    }
    #pragma unroll
    for (int off = 32; off; off >>= 1) {
      ssum += __shfl_xor(ssum, off);
      wsum += __shfl_xor(wsum, off);
      const float ov = __shfl_xor(bv, off);
      const int   oi = __shfl_xor(bi, off);
      if (ov > bv || (ov == bv && oi < bi)) { bv = ov; bi = oi; }
    }
    const float inv = 1.0f / (ssum + 1e-8f);
    const int hi = bi;  // wave-uniform argmax

    float t0 = 0.f, t1 = 0.f;
    #pragma unroll
    for (int k = 0; k < 8; k++) {
      const float att = e[k] * inv;
      cacc[k] += att;
      if (jmap[k] >= hi - 1 && jmap[k] <= hi + 1) {
        const float pr = LOWER ? fmaxf((float)(i - jmap[k]) * pscale, 0.f)
                               : fmaxf((float)(jmap[k] - i) * pscale, 0.f);
        t0 += att;
        t1 += att * pr;
      }
    }
    #pragma unroll
    for (int off = 32; off; off >>= 1) {
      t0 += __shfl_xor(t0, off);
      t1 += __shfl_xor(t1, off);
    }
    if (lane == 0) {
      disp_ini[h * W + i] = (float)i - wsum * inv;
      raw[h * W + i]      = t1 / (t0 < 0.1f ? 1.0f : t0);
    }
  }

  // column-sum reduction: regs -> LDS (cross-wave) -> global (cross-block)
  #pragma unroll
  for (int k = 0; k < 8; k++) atomicAdd(&scol[jmap[k]], cacc[k]);
  __syncthreads();
  atomicAdd(&colsum[h * W + tid], scol[tid]);
}

// ---------------------------------------------------------------------------
// Kernel 2: closed-form hole fill (the W-step scan converges to this):
//   valid i            -> disp_ini[i]
//   invalid, valid p<i -> disp_ini[p] * (1+1e-4)^-(i-p)   (left-to-right pass)
//   invalid prefix     -> disp_ini[p0] * (1+1e-4)^-(p0-i) (right-to-left pass)
//   no valid in row    -> 0
// One wave per (pair, h) row.
// ---------------------------------------------------------------------------
__global__ __launch_bounds__(64) void fill_rows(
    const float* __restrict__ dispA, const float* __restrict__ csA,
    const float* __restrict__ dispB, const float* __restrict__ csB,
    float* __restrict__ out)
{
  __shared__ float xrow[W];
  const int pair = blockIdx.x >> 6;   // 0: ch0 (r2l disp, vm_left), 1: ch1
  const int h    = blockIdx.x & 63;
  const float* dsp = (pair ? dispB : dispA) + h * W;
  const float* cs  = (pair ? csB  : csA ) + h * W;
  float* o = out + pair * (H * W) + h * W;
  const int lane = threadIdx.x;
  const int j0 = lane * 8;

  float x[8];
  bool m[8];
  int incl[8];
  int run = -1, fv = W;
  #pragma unroll
  for (int k = 0; k < 8; k++) {
    x[k] = dsp[j0 + k];
    m[k] = cs[j0 + k] > 0.1f;
    xrow[j0 + k] = x[k];
    if (m[k]) { run = j0 + k; if (fv == W) fv = j0 + k; }
    incl[k] = run;
  }
  // inclusive max-scan across lanes of "last valid index in my segment"
  int v = run;
  #pragma unroll
  for (int off = 1; off < 64; off <<= 1) {
    const int tv = __shfl_up(v, off);
    if (lane >= off) v = max(v, tv);
  }
  int excl = __shfl_up(v, 1);
  if (lane == 0) excl = -1;
  // first valid index in the whole row
  int p0 = fv;
  #pragma unroll
  for (int off = 32; off; off >>= 1) p0 = min(p0, __shfl_xor(p0, off));
  __syncthreads();

  const float C2 = -1.4426229e-4f;  // -log2(1 + 1e-4)
  #pragma unroll
  for (int k = 0; k < 8; k++) {
    const int jj = j0 + k;
    float ov;
    if (m[k]) {
      ov = x[k];
    } else {
      const int p = max(excl, incl[k]);
      if (p >= 0)        ov = xrow[p]  * exp2f(C2 * (float)(jj - p));
      else if (p0 < W)   ov = xrow[p0] * exp2f(C2 * (float)(p0 - jj));
      else               ov = 0.f;
    }
    o[jj] = ov;
  }
}

extern "C" void kernel_launch(void* const* d_in, const int* in_sizes, int n_in,
                              void* d_out, int out_size, void* d_ws, size_t ws_size,
                              hipStream_t stream) {
  const float* cost1 = (const float*)d_in[0];  // -> att_l2r (triu)
  const float* cost2 = (const float*)d_in[1];  // -> att_r2l (tril)
  float* out = (float*)d_out;                  // [4, H, W]
  float* w = (float*)d_ws;
  float* disp_r2l_ini = w;                     // 32768 floats (from cost2)
  float* disp_l2r_ini = w + 32768;             // (from cost1)
  float* cs_l2r       = w + 65536;             // colsums of att_l2r -> vm_left
  float* cs_r2l       = w + 98304;             // colsums of att_r2l -> vm_right

  hipMemsetAsync(cs_l2r, 0, 2 * (size_t)H * W * sizeof(float), stream);

  // ch2 = raw_l2r = gen_raw_disp(att_r2l, pos);  ch3 = raw_r2l (pos^T)
  attn_stats<true ><<<H * SPLIT, 512, 0, stream>>>(cost2, disp_r2l_ini, cs_r2l,
                                                   out + 2 * H * W);
  attn_stats<false><<<H * SPLIT, 512, 0, stream>>>(cost1, disp_l2r_ini, cs_l2r,
                                                   out + 3 * H * W);
  // ch0 = regress(att_r2l, vm_left); ch1 = regress(att_l2r, vm_right)
  fill_rows<<<2 * H, 64, 0, stream>>>(disp_r2l_ini, cs_l2r,
                                      disp_l2r_ini, cs_r2l, out);
}

// Round 2
// 170.773 us; speedup vs baseline: 1.1543x; 1.1543x over previous
//
#include <hip/hip_runtime.h>
#include <float.h>

#define H 64
#define W 512
#define SPLIT 8   // blocks per (tensor,h): 2*64*8 = 1024 blocks = 4 blocks/CU

// ---------------------------------------------------------------------------
// Fused masked-exp-norm row statistics for BOTH cost volumes in one dispatch.
// Per row i of a [H,W,W] cost volume, without materializing att:
//   disp_ini[i] = i - sum_j att[i,j]*j
//   colsum[j]  += sum_i att[i,j]          (-> valid mask, thresholded later)
//   raw[i]      = 3-tap subpixel around argmax (gen_raw_disp fused)
// lower=true  (cost2 -> att_r2l): tril mask (j<=i), pos = (i-j)*pscale
// lower=false (cost1 -> att_l2r): triu mask (j>=i), pos = (j-i)*pscale
// Argmax is fused into the max-reduction: argmax(att) == first-occurrence
// argmax of c over valid j (exp monotone; valid e>0 >= masked 0, and the max
// tap has e==1 so it always beats the zeros).
// ---------------------------------------------------------------------------
__global__ __launch_bounds__(512) void attn_stats_all(
    const float* __restrict__ cost1, const float* __restrict__ cost2,
    float* __restrict__ disp_r2l, float* __restrict__ disp_l2r,
    float* __restrict__ cs_r2l,  float* __restrict__ cs_l2r,
    float* __restrict__ out)
{
  __shared__ float scol[W];
  const int tid  = threadIdx.x;
  const int lane = tid & 63;
  const int wid  = tid >> 6;              // 0..7
  const int gid  = blockIdx.x;
  const bool lower = (gid & 1) == 0;      // interleave tensors across CUs/XCDs
  const int rest = gid >> 1;
  const int h    = rest / SPLIT;
  const int s    = rest % SPLIT;

  const float* cost = lower ? cost2 : cost1;
  float* disp = lower ? disp_r2l : disp_l2r;
  float* csum = lower ? cs_r2l  : cs_l2r;
  float* raw  = out + (lower ? 2 : 3) * (H * W);

  scol[tid] = 0.f;
  __syncthreads();

  float cacc[8] = {0,0,0,0,0,0,0,0};
  const float pscale = 2.0f / 511.0f;     // linspace(0,2,512) step
  const float* hb = cost + (size_t)h * W * W;

  int jmap[8];
  #pragma unroll
  for (int k = 0; k < 8; k++)
    jmap[k] = (k < 4) ? (lane * 4 + k) : (256 + lane * 4 + (k - 4));

  for (int t = wid; t < W / SPLIT; t += 8) {
    const int i = s * (W / SPLIT) + t;
    const float* rp = hb + (size_t)i * W;
    const float4 va = ((const float4*)rp)[lane];       // j = lane*4+k
    const float4 vb = ((const float4*)rp)[64 + lane];  // j = 256+lane*4+(k-4)
    float c[8] = {va.x, va.y, va.z, va.w, vb.x, vb.y, vb.z, vb.w};

    // ---- fused max + argmax over valid entries (first occurrence on ties)
    bool vld[8];
    float mxv = -FLT_MAX;
    int   bj  = W;
    #pragma unroll
    for (int k = 0; k < 8; k++) {
      vld[k] = lower ? (jmap[k] <= i) : (jmap[k] >= i);
      if (vld[k] && c[k] > mxv) { mxv = c[k]; bj = jmap[k]; }  // j ascending in k
    }
    #pragma unroll
    for (int off = 32; off; off >>= 1) {
      const float ov = __shfl_xor(mxv, off);
      const int   oj = __shfl_xor(bj, off);
      if (ov > mxv || (ov == mxv && oj < bj)) { mxv = ov; bj = oj; }
    }
    const int hi = bj;                    // wave-uniform argmax
    float mx = mxv;
    // tril/triu zeros participate in the exp-max whenever the row has any
    if (lower ? (i < W - 1) : (i > 0)) mx = fmaxf(mx, 0.f);

    // ---- exp + row sums + 3-tap partials
    float e[8];
    float ssum = 0.f, wsum = 0.f, s0 = 0.f, s1 = 0.f;
    #pragma unroll
    for (int k = 0; k < 8; k++) {
      e[k] = vld[k] ? __expf(c[k] - mx) : 0.f;
      ssum += e[k];
      wsum += e[k] * (float)jmap[k];
      if (jmap[k] >= hi - 1 && jmap[k] <= hi + 1) {
        const float pr = fmaxf((float)(lower ? (i - jmap[k]) : (jmap[k] - i)) * pscale, 0.f);
        s0 += e[k];
        s1 += e[k] * pr;
      }
    }
    #pragma unroll
    for (int off = 32; off; off >>= 1) {
      ssum += __shfl_xor(ssum, off);
      wsum += __shfl_xor(wsum, off);
    }
    const float inv = 1.0f / (ssum + 1e-8f);

    // ---- gather 3-tap partials: taps around uniform hi live in <=2 lanes
    const int jlo = hi > 0 ? hi - 1 : 0;
    const int jh2 = hi < W - 1 ? hi + 1 : W - 1;
    const int l1 = (jlo & 255) >> 2;
    const int l2 = (jh2 & 255) >> 2;
    float t0 = __shfl(s0, l1), t1 = __shfl(s1, l1);
    if (l2 != l1) { t0 += __shfl(s0, l2); t1 += __shfl(s1, l2); }

    #pragma unroll
    for (int k = 0; k < 8; k++) cacc[k] += e[k] * inv;

    if (lane == 0) {
      disp[h * W + i] = (float)i - wsum * inv;
      const float n0 = t0 * inv;                 // sum of the 3 att taps
      raw[h * W + i]  = (t1 * inv) / (n0 < 0.1f ? 1.0f : n0);
    }
  }

  // column-sum reduction: regs -> LDS (cross-wave) -> global (cross-block)
  #pragma unroll
  for (int k = 0; k < 8; k++) atomicAdd(&scol[jmap[k]], cacc[k]);
  __syncthreads();
  atomicAdd(&csum[h * W + tid], scol[tid]);
}

// ---------------------------------------------------------------------------
// Closed-form hole fill (the W-step scan converges to this):
//   valid i            -> disp_ini[i]
//   invalid, valid p<i -> disp_ini[p] * (1+1e-4)^-(i-p)   (left-to-right pass)
//   invalid prefix     -> disp_ini[p0] * (1+1e-4)^-(p0-i) (right-to-left pass)
//   no valid in row    -> 0
// One wave per (pair, h) row.
// ---------------------------------------------------------------------------
__global__ __launch_bounds__(64) void fill_rows(
    const float* __restrict__ dispA, const float* __restrict__ csA,
    const float* __restrict__ dispB, const float* __restrict__ csB,
    float* __restrict__ out)
{
  __shared__ float xrow[W];
  const int pair = blockIdx.x >> 6;   // 0: ch0 (r2l disp, vm_left), 1: ch1
  const int h    = blockIdx.x & 63;
  const float* dsp = (pair ? dispB : dispA) + h * W;
  const float* cs  = (pair ? csB  : csA ) + h * W;
  float* o = out + pair * (H * W) + h * W;
  const int lane = threadIdx.x;
  const int j0 = lane * 8;

  float x[8];
  bool m[8];
  int incl[8];
  int run = -1, fv = W;
  #pragma unroll
  for (int k = 0; k < 8; k++) {
    x[k] = dsp[j0 + k];
    m[k] = cs[j0 + k] > 0.1f;
    xrow[j0 + k] = x[k];
    if (m[k]) { run = j0 + k; if (fv == W) fv = j0 + k; }
    incl[k] = run;
  }
  // inclusive max-scan across lanes of "last valid index in my segment"
  int v = run;
  #pragma unroll
  for (int off = 1; off < 64; off <<= 1) {
    const int tv = __shfl_up(v, off);
    if (lane >= off) v = max(v, tv);
  }
  int excl = __shfl_up(v, 1);
  if (lane == 0) excl = -1;
  // first valid index in the whole row
  int p0 = fv;
  #pragma unroll
  for (int off = 32; off; off >>= 1) p0 = min(p0, __shfl_xor(p0, off));
  __syncthreads();

  const float C2 = -1.4426229e-4f;  // -log2(1 + 1e-4)
  #pragma unroll
  for (int k = 0; k < 8; k++) {
    const int jj = j0 + k;
    float ov;
    if (m[k]) {
      ov = x[k];
    } else {
      const int p = max(excl, incl[k]);
      if (p >= 0)        ov = xrow[p]  * exp2f(C2 * (float)(jj - p));
      else if (p0 < W)   ov = xrow[p0] * exp2f(C2 * (float)(p0 - jj));
      else               ov = 0.f;
    }
    o[jj] = ov;
  }
}

extern "C" void kernel_launch(void* const* d_in, const int* in_sizes, int n_in,
                              void* d_out, int out_size, void* d_ws, size_t ws_size,
                              hipStream_t stream) {
  const float* cost1 = (const float*)d_in[0];  // -> att_l2r (triu)
  const float* cost2 = (const float*)d_in[1];  // -> att_r2l (tril)
  float* out = (float*)d_out;                  // [4, H, W]
  float* w = (float*)d_ws;
  float* disp_r2l_ini = w;                     // 32768 floats (from cost2)
  float* disp_l2r_ini = w + 32768;             // (from cost1)
  float* cs_l2r       = w + 65536;             // colsums of att_l2r -> vm_left
  float* cs_r2l       = w + 98304;             // colsums of att_r2l -> vm_right

  hipMemsetAsync(cs_l2r, 0, 2 * (size_t)H * W * sizeof(float), stream);

  attn_stats_all<<<2 * H * SPLIT, 512, 0, stream>>>(
      cost1, cost2, disp_r2l_ini, disp_l2r_ini, cs_r2l, cs_l2r, out);

  // ch0 = regress(att_r2l, vm_left); ch1 = regress(att_l2r, vm_right)
  fill_rows<<<2 * H, 64, 0, stream>>>(disp_r2l_ini, cs_l2r,
                                      disp_l2r_ini, cs_r2l, out);
}